// Round 1
// baseline (872.610 us; speedup 1.0000x reference)
//
#include <hip/hip_runtime.h>

#define NVAR 100000
#define NCON 50000
#define DVAR 8
#define DCON 16
#define DIN 32
#define DH 128
#define DCAT 288

__device__ __forceinline__ float f4c(const float4& v, int kk) {
    switch (kk) { case 0: return v.x; case 1: return v.y; case 2: return v.z; default: return v.w; }
}

// ---------------------------------------------------------------- init: h = x @ W + b
__global__ __launch_bounds__(256) void init_kernel(
    const float* __restrict__ x,
    const float* __restrict__ Wv, const float* __restrict__ bv,
    const float* __restrict__ Wc, const float* __restrict__ bc,
    float* __restrict__ v, float* __restrict__ c)
{
    const int t = threadIdx.x;
    const int n = t & 127;
    const int rsub = t >> 7;                 // 0..1
    const int rbase = blockIdx.x * 8;
    #pragma unroll
    for (int rr = 0; rr < 4; ++rr) {
        int row = rbase + rr * 2 + rsub;
        if (row >= NVAR + NCON) return;
        const float* W; const float* b; float* o; int orow;
        if (row < NVAR) { W = Wv; b = bv; o = v; orow = row; }
        else            { W = Wc; b = bc; o = c; orow = row - NVAR; }
        float acc = b[n];
        const float* xr = x + (size_t)row * DIN;
        #pragma unroll
        for (int k = 0; k < DIN; ++k) acc += xr[k] * W[k * DH + n];
        o[(size_t)orow * DH + n] = acc;
    }
}

// ---------------------------------------------------------------- fused layer:
//   h_out = [sum_nb(h_nb[idx]), h_self, x_self] @ W + b
// 64 rows/block, 256 threads; agg staged in LDS; h_self/x_self read from global (L1-hot strips)
template<int DEG>
__global__ __launch_bounds__(256, 3) void layer_kernel(
    const float* __restrict__ h_self,
    const float* __restrict__ h_nb,
    const float* __restrict__ x_self,
    const int*   __restrict__ idx,
    const float* __restrict__ W,     // DCAT x DH
    const float* __restrict__ b,
    float* __restrict__ h_out,
    int M)
{
    __shared__ __align__(16) float As[64][132];  // agg part only (pad 132: 2-way max on reads)
    const int t = threadIdx.x;
    const int r0 = blockIdx.x * 64;

    // ---- Phase 1: neighbor aggregation into As[r][0:128]
    {
        const int q = t & 31;        // 4-float quad within row
        const int rb = t >> 5;       // 0..7
        for (int rr = rb; rr < 64; rr += 8) {
            int row = r0 + rr;
            int rowc = row < M ? row : M - 1;   // clamp (garbage rows discarded at write)
            int nbid[DEG];
            #pragma unroll
            for (int dd = 0; dd < DEG / 4; ++dd)
                *reinterpret_cast<int4*>(&nbid[4 * dd]) =
                    *reinterpret_cast<const int4*>(idx + (size_t)rowc * DEG + 4 * dd);
            float4 acc = make_float4(0.f, 0.f, 0.f, 0.f);
            #pragma unroll
            for (int d = 0; d < DEG; ++d) {
                const float4 val = *reinterpret_cast<const float4*>(
                    h_nb + (size_t)nbid[d] * DH + q * 4);
                acc.x += val.x; acc.y += val.y; acc.z += val.z; acc.w += val.w;
            }
            *reinterpret_cast<float4*>(&As[rr][q * 4]) = acc;
        }
    }
    __syncthreads();

    // ---- Phase 2: GEMM (64 x 288) @ (288 x 128), 4 rows x 8 cols per thread
    const int tn = t & 15;
    const int tm = t >> 4;           // 0..15
    const int rm = tm * 4;
    const int cn = tn * 4;           // cols cn..cn+3 and cn+64..cn+67
    const int row0 = r0 + rm;
    int rc[4];
    #pragma unroll
    for (int i = 0; i < 4; ++i) { int r = row0 + i; rc[i] = r < M ? r : M - 1; }

    float acc[4][8];
    #pragma unroll
    for (int i = 0; i < 4; ++i)
        #pragma unroll
        for (int j = 0; j < 8; ++j) acc[i][j] = 0.f;

    // Segment 1: k in [0,128) — A from LDS (agg)
    #pragma unroll 2
    for (int k = 0; k < DH; k += 4) {
        float4 a4[4];
        #pragma unroll
        for (int i = 0; i < 4; ++i)
            a4[i] = *reinterpret_cast<const float4*>(&As[rm + i][k]);
        #pragma unroll
        for (int kk = 0; kk < 4; ++kk) {
            float4 w0 = *reinterpret_cast<const float4*>(W + (size_t)(k + kk) * DH + cn);
            float4 w1 = *reinterpret_cast<const float4*>(W + (size_t)(k + kk) * DH + cn + 64);
            #pragma unroll
            for (int i = 0; i < 4; ++i) {
                float a = f4c(a4[i], kk);
                acc[i][0] += a * w0.x; acc[i][1] += a * w0.y;
                acc[i][2] += a * w0.z; acc[i][3] += a * w0.w;
                acc[i][4] += a * w1.x; acc[i][5] += a * w1.y;
                acc[i][6] += a * w1.z; acc[i][7] += a * w1.w;
            }
        }
    }
    // Segment 2: k in [128,256) — A from h_self (global, L1-hot column strip)
    #pragma unroll 2
    for (int k = 0; k < DH; k += 4) {
        float4 a4[4];
        #pragma unroll
        for (int i = 0; i < 4; ++i)
            a4[i] = *reinterpret_cast<const float4*>(h_self + (size_t)rc[i] * DH + k);
        #pragma unroll
        for (int kk = 0; kk < 4; ++kk) {
            float4 w0 = *reinterpret_cast<const float4*>(W + (size_t)(DH + k + kk) * DH + cn);
            float4 w1 = *reinterpret_cast<const float4*>(W + (size_t)(DH + k + kk) * DH + cn + 64);
            #pragma unroll
            for (int i = 0; i < 4; ++i) {
                float a = f4c(a4[i], kk);
                acc[i][0] += a * w0.x; acc[i][1] += a * w0.y;
                acc[i][2] += a * w0.z; acc[i][3] += a * w0.w;
                acc[i][4] += a * w1.x; acc[i][5] += a * w1.y;
                acc[i][6] += a * w1.z; acc[i][7] += a * w1.w;
            }
        }
    }
    // Segment 3: k in [256,288) — A from x_self
    #pragma unroll 2
    for (int k = 0; k < DIN; k += 4) {
        float4 a4[4];
        #pragma unroll
        for (int i = 0; i < 4; ++i)
            a4[i] = *reinterpret_cast<const float4*>(x_self + (size_t)rc[i] * DIN + k);
        #pragma unroll
        for (int kk = 0; kk < 4; ++kk) {
            float4 w0 = *reinterpret_cast<const float4*>(W + (size_t)(2 * DH + k + kk) * DH + cn);
            float4 w1 = *reinterpret_cast<const float4*>(W + (size_t)(2 * DH + k + kk) * DH + cn + 64);
            #pragma unroll
            for (int i = 0; i < 4; ++i) {
                float a = f4c(a4[i], kk);
                acc[i][0] += a * w0.x; acc[i][1] += a * w0.y;
                acc[i][2] += a * w0.z; acc[i][3] += a * w0.w;
                acc[i][4] += a * w1.x; acc[i][5] += a * w1.y;
                acc[i][6] += a * w1.z; acc[i][7] += a * w1.w;
            }
        }
    }

    // ---- Epilogue: + bias, store
    #pragma unroll
    for (int i = 0; i < 4; ++i) {
        int row = row0 + i;
        if (row < M) {
            float4 o0, o1;
            o0.x = acc[i][0] + b[cn + 0]; o0.y = acc[i][1] + b[cn + 1];
            o0.z = acc[i][2] + b[cn + 2]; o0.w = acc[i][3] + b[cn + 3];
            o1.x = acc[i][4] + b[cn + 64]; o1.y = acc[i][5] + b[cn + 65];
            o1.z = acc[i][6] + b[cn + 66]; o1.w = acc[i][7] + b[cn + 67];
            *reinterpret_cast<float4*>(h_out + (size_t)row * DH + cn) = o0;
            *reinterpret_cast<float4*>(h_out + (size_t)row * DH + cn + 64) = o1;
        }
    }
}

// ---------------------------------------------------------------- column-sum partials of v
__global__ __launch_bounds__(256) void reduce_kernel(
    const float* __restrict__ v, float* __restrict__ part)
{
    __shared__ float sred[256];
    const int t = threadIdx.x;
    const int col = t & 127;
    const int half = t >> 7;
    float local = 0.f;
    for (int r = blockIdx.x * 2 + half; r < NVAR; r += 256)
        local += v[(size_t)r * DH + col];
    sred[t] = local;
    __syncthreads();
    if (t < 128) part[blockIdx.x * DH + t] = sred[t] + sred[t + 128];
}

// ---------------------------------------------------------------- s = g . Wq[0:128] + bq
__global__ __launch_bounds__(256) void finalize_kernel(
    const float* __restrict__ part, const float* __restrict__ Wq,
    const float* __restrict__ bq, float* __restrict__ sout)
{
    __shared__ float sred[256];
    const int t = threadIdx.x;
    const int col = t & 127;
    const int half = t >> 7;
    float gp = 0.f;
    #pragma unroll 4
    for (int bb = half; bb < 128; bb += 2) gp += part[(size_t)bb * DH + col];
    sred[t] = gp * Wq[col];
    __syncthreads();
    if (t < 128) sred[t] += sred[t + 128];
    __syncthreads();
    if (t < 64) {
        float val = sred[t] + sred[t + 64];
        #pragma unroll
        for (int off = 32; off > 0; off >>= 1) val += __shfl_down(val, off);
        if (t == 0) sout[0] = val + bq[0];
    }
}

// ---------------------------------------------------------------- out[i] = s + v[i] . Wq[128:256]
__global__ __launch_bounds__(256) void out_kernel(
    const float* __restrict__ v, const float* __restrict__ Wq,
    const float* __restrict__ sIn, float* __restrict__ outp)
{
    const int lane = threadIdx.x & 63;
    const int wave = blockIdx.x * 4 + (threadIdx.x >> 6);
    const float wq0 = Wq[DH + lane];
    const float wq1 = Wq[DH + 64 + lane];
    const float s = sIn[0];
    const int rbase = wave * 64;
    #pragma unroll 4
    for (int rr = 0; rr < 64; ++rr) {
        int r = rbase + rr;
        if (r >= NVAR) continue;
        float val = v[(size_t)r * DH + lane] * wq0 + v[(size_t)r * DH + 64 + lane] * wq1;
        #pragma unroll
        for (int off = 32; off > 0; off >>= 1) val += __shfl_down(val, off);
        if (lane == 0) outp[r] = s + val;
    }
}

extern "C" void kernel_launch(void* const* d_in, const int* in_sizes, int n_in,
                              void* d_out, int out_size, void* d_ws, size_t ws_size,
                              hipStream_t stream)
{
    const float* x    = (const float*)d_in[0];
    const int*   vci  = (const int*)  d_in[1];   // NVAR x 8, values < NCON
    const int*   cvi  = (const int*)  d_in[2];   // NCON x 16, values < NVAR
    const float* Wiv  = (const float*)d_in[3];
    const float* biv  = (const float*)d_in[4];
    const float* Wic  = (const float*)d_in[5];
    const float* bic  = (const float*)d_in[6];
    const float* Wvar = (const float*)d_in[7];
    const float* bvar = (const float*)d_in[8];
    const float* Wcon = (const float*)d_in[9];
    const float* bcon = (const float*)d_in[10];
    const float* Wq   = (const float*)d_in[11];
    const float* bq   = (const float*)d_in[12];
    float* outp = (float*)d_out;

    float* ws = (float*)d_ws;
    size_t off = 0;
    float* vA = ws + off; off += (size_t)NVAR * DH;
    float* vB = ws + off; off += (size_t)NVAR * DH;
    float* cA = ws + off; off += (size_t)NCON * DH;
    float* cB = ws + off; off += (size_t)NCON * DH;
    float* part = ws + off; off += 128 * DH;
    float* sbuf = ws + off; off += 1;

    // init: v0, c0
    init_kernel<<<(NVAR + NCON) / 8, 256, 0, stream>>>(x, Wiv, biv, Wic, bic, vA, cA);
    // layer 1: c1 = f(agg(v0), c0, xc); v1 = f(agg(c0), v0, xv)
    layer_kernel<DCON><<<(NCON + 63) / 64, 256, 0, stream>>>(
        cA, vA, x + (size_t)NVAR * DIN, cvi, Wcon, bcon, cB, NCON);
    layer_kernel<DVAR><<<(NVAR + 63) / 64, 256, 0, stream>>>(
        vA, cA, x, vci, Wvar, bvar, vB, NVAR);
    // layer 2: only v2 needed (c2 is dead in the reference)
    layer_kernel<DVAR><<<(NVAR + 63) / 64, 256, 0, stream>>>(
        vB, cB, x, vci, Wvar, bvar, vA, NVAR);
    // readout
    reduce_kernel<<<128, 256, 0, stream>>>(vA, part);
    finalize_kernel<<<1, 256, 0, stream>>>(part, Wq, bq, sbuf);
    out_kernel<<<(NVAR + 255) / 256, 256, 0, stream>>>(vA, Wq, sbuf, outp);
}